// Round 1
// baseline (256.273 us; speedup 1.0000x reference)
//
#include <hip/hip_runtime.h>

#define LN 262144
#define LMASK 262143
#define NCH 64
#define NMODE 64
#define TWO_PI 6.2831853071795864769f

// ---------------- K1: forward DFT partial sums ----------------
// grid: nb blocks x 256 threads. Block b handles rows [b*chunk, (b+1)*chunk).
// thread: cg = tid&7 -> channels cg*8..cg*8+7 ; mg = tid>>3 -> modes 2*mg, 2*mg+1
// partials (floats): part[b*8192 +    0 + k*64 + i] = Re sum
//                    part[b*8192 + 4096 + k*64 + i] = Im sum
__global__ __launch_bounds__(256) void fno_fwd(const float* __restrict__ u,
                                               float* __restrict__ part, int nb) {
    const int tid = threadIdx.x;
    const int cg = tid & 7;
    const int mg = tid >> 3;
    const int k0 = mg * 2;
    const int chunk = LN / nb;
    const int n0 = blockIdx.x * chunk;

    float re0[8] = {0,0,0,0,0,0,0,0};
    float im0[8] = {0,0,0,0,0,0,0,0};
    float re1[8] = {0,0,0,0,0,0,0,0};
    float im1[8] = {0,0,0,0,0,0,0,0};

    // per-row rotation steps e^{+i*2*pi*k/L}; accumulate Re += u*cos, Im -= u*sin
    float ck0, sk0, ck1, sk1;
    __sincosf((float)k0 * (TWO_PI / (float)LN), &sk0, &ck0);
    __sincosf((float)(k0 + 1) * (TWO_PI / (float)LN), &sk1, &ck1);

    const float* __restrict__ ubase = u + (size_t)n0 * NCH + cg * 8;

    for (int seg = 0; seg < chunk; seg += 2048) {
        const int segLen = min(2048, chunk - seg);
        float c0, s0, c1, s1;
        {
            const int ph0 = (k0 * (n0 + seg)) & LMASK;
            const int ph1 = ((k0 + 1) * (n0 + seg)) & LMASK;
            __sincosf((float)ph0 * (TWO_PI / (float)LN), &s0, &c0);
            __sincosf((float)ph1 * (TWO_PI / (float)LN), &s1, &c1);
        }
        const float* __restrict__ p = ubase + (size_t)seg * NCH;
        #pragma unroll 4
        for (int r = 0; r < segLen; ++r) {
            float4 va = *(const float4*)(p);
            float4 vb = *(const float4*)(p + 4);
            p += NCH;
            float uv[8] = {va.x, va.y, va.z, va.w, vb.x, vb.y, vb.z, vb.w};
            #pragma unroll
            for (int q = 0; q < 8; ++q) {
                re0[q] = fmaf(c0, uv[q], re0[q]);
                im0[q] = fmaf(-s0, uv[q], im0[q]);
                re1[q] = fmaf(c1, uv[q], re1[q]);
                im1[q] = fmaf(-s1, uv[q], im1[q]);
            }
            float t0 = c0 * ck0 - s0 * sk0;
            s0 = s0 * ck0 + c0 * sk0;
            c0 = t0;
            float t1 = c1 * ck1 - s1 * sk1;
            s1 = s1 * ck1 + c1 * sk1;
            c1 = t1;
        }
    }

    float* __restrict__ base = part + (size_t)blockIdx.x * 8192;
    *(float4*)(base + k0 * 64 + cg * 8)           = make_float4(re0[0], re0[1], re0[2], re0[3]);
    *(float4*)(base + k0 * 64 + cg * 8 + 4)       = make_float4(re0[4], re0[5], re0[6], re0[7]);
    *(float4*)(base + (k0 + 1) * 64 + cg * 8)     = make_float4(re1[0], re1[1], re1[2], re1[3]);
    *(float4*)(base + (k0 + 1) * 64 + cg * 8 + 4) = make_float4(re1[4], re1[5], re1[6], re1[7]);
    base += 4096;
    *(float4*)(base + k0 * 64 + cg * 8)           = make_float4(im0[0], im0[1], im0[2], im0[3]);
    *(float4*)(base + k0 * 64 + cg * 8 + 4)       = make_float4(im0[4], im0[5], im0[6], im0[7]);
    *(float4*)(base + (k0 + 1) * 64 + cg * 8)     = make_float4(im1[0], im1[1], im1[2], im1[3]);
    *(float4*)(base + (k0 + 1) * 64 + cg * 8 + 4) = make_float4(im1[4], im1[5], im1[6], im1[7]);
}

// ---------------- K2: reduce partials + apply Kc + z_local -> coefficients ----------------
// grid: 64 blocks (one per mode k), 256 threads.
// coef[k*64+o]        = A[k][o]  (cos coefficient; k=0 also holds z_local)
// coef[4096 + k*64+o] = B[k][o]  (sin coefficient)
__global__ __launch_bounds__(256) void fno_coef(const float* __restrict__ part, int nb,
                                                const float* __restrict__ Kt,
                                                const float* __restrict__ W,
                                                const float* __restrict__ u,
                                                const float* __restrict__ y,
                                                float* __restrict__ coef) {
    const int k = blockIdx.x;
    const int tid = threadIdx.x;
    const int i = tid & 63;
    const int q = tid >> 6;  // 0..3

    float re = 0.0f, im = 0.0f;
    for (int b = q; b < nb; b += 4) {
        const float* p = part + (size_t)b * 8192 + k * 64 + i;
        re += p[0];
        im += p[4096];
    }
    __shared__ float rs[4][64], is[4][64];
    rs[q][i] = re;
    is[q][i] = im;
    __syncthreads();
    __shared__ float reU[64], imU[64];
    if (tid < 64) {
        reU[tid] = rs[0][tid] + rs[1][tid] + rs[2][tid] + rs[3][tid];
        imU[tid] = is[0][tid] + is[1][tid] + is[2][tid] + is[3][tid];
    }
    __syncthreads();

    if (tid < 64) {
        const int o = tid;
        // z[k][o] = sum_i u_hat[k,i] * (K0[i,o,k] + i*K1[i,o,k])
        float zr = 0.0f, zi = 0.0f;
        for (int ii = 0; ii < 64; ++ii) {
            const float k0v = Kt[(size_t)(ii * 64 + o) * 64 + k];
            const float k1v = Kt[(size_t)262144 + (size_t)(ii * 64 + o) * 64 + k];
            zr += reU[ii] * k0v - imU[ii] * k1v;
            zi += reU[ii] * k1v + imU[ii] * k0v;
        }
        const float invL = 1.0f / (float)LN;
        float A, B;
        if (k == 0) {
            const int idx = (int)(y[0] * (float)LN);
            float zl = 0.0f;
            for (int ii = 0; ii < 64; ++ii)
                zl += W[o * 64 + ii] * u[(size_t)idx * 64 + ii];
            A = zr * invL + zl;   // irfft uses only Re of DC bin; fold z_local here
            B = 0.0f;
        } else {
            A = 2.0f * zr * invL;
            B = -2.0f * zi * invL;
        }
        coef[k * 64 + o] = A;
        coef[4096 + k * 64 + o] = B;
    }
}

// ---------------- K3: inverse (64-mode Fourier series) + write out ----------------
// grid: 1024 blocks x 256 threads; block covers 256 rows.
// thread: cg = tid&7 (channels cg*8..+7), rg = tid>>3 (8 consecutive rows).
// out[n,o] = sum_k A[k][o]*cos(2*pi*k*n/L) + B[k][o]*sin(2*pi*k*n/L)
__global__ __launch_bounds__(256) void fno_inv(const float* __restrict__ coef,
                                               float* __restrict__ out) {
    __shared__ float As[NMODE][NCH];
    __shared__ float Bs[NMODE][NCH];
    const int tid = threadIdx.x;
    for (int e = tid; e < 4096; e += 256) {
        As[e >> 6][e & 63] = coef[e];
        Bs[e >> 6][e & 63] = coef[4096 + e];
    }
    __syncthreads();

    const int cg = tid & 7;
    const int rg = tid >> 3;
    const int n0 = blockIdx.x * 256 + rg * 8;

    float cst[8], sst[8], cr[8], sr[8];
    #pragma unroll
    for (int r = 0; r < 8; ++r) {
        __sincosf((float)(n0 + r) * (TWO_PI / (float)LN), &sst[r], &cst[r]);
        cr[r] = 1.0f;
        sr[r] = 0.0f;
    }
    float acc[8][8];
    #pragma unroll
    for (int r = 0; r < 8; ++r)
        #pragma unroll
        for (int qq = 0; qq < 8; ++qq) acc[r][qq] = 0.0f;

    for (int k = 0; k < NMODE; ++k) {
        float4 a0 = *(const float4*)&As[k][cg * 8];
        float4 a1 = *(const float4*)&As[k][cg * 8 + 4];
        float4 b0 = *(const float4*)&Bs[k][cg * 8];
        float4 b1 = *(const float4*)&Bs[k][cg * 8 + 4];
        float av[8] = {a0.x, a0.y, a0.z, a0.w, a1.x, a1.y, a1.z, a1.w};
        float bv[8] = {b0.x, b0.y, b0.z, b0.w, b1.x, b1.y, b1.z, b1.w};
        #pragma unroll
        for (int r = 0; r < 8; ++r) {
            #pragma unroll
            for (int qq = 0; qq < 8; ++qq)
                acc[r][qq] = fmaf(av[qq], cr[r], fmaf(bv[qq], sr[r], acc[r][qq]));
            float t = cr[r] * cst[r] - sr[r] * sst[r];
            sr[r] = sr[r] * cst[r] + cr[r] * sst[r];
            cr[r] = t;
        }
    }
    #pragma unroll
    for (int r = 0; r < 8; ++r) {
        float* po = out + (size_t)(n0 + r) * NCH + cg * 8;
        *(float4*)(po)     = make_float4(acc[r][0], acc[r][1], acc[r][2], acc[r][3]);
        *(float4*)(po + 4) = make_float4(acc[r][4], acc[r][5], acc[r][6], acc[r][7]);
    }
}

extern "C" void kernel_launch(void* const* d_in, const int* in_sizes, int n_in,
                              void* d_out, int out_size, void* d_ws, size_t ws_size,
                              hipStream_t stream) {
    const float* u = (const float*)d_in[0];
    const float* y = (const float*)d_in[1];
    const float* K = (const float*)d_in[2];
    const float* W = (const float*)d_in[3];
    float* out = (float*)d_out;
    float* ws = (float*)d_ws;

    // choose number of forward blocks (power of two) to fit partials + coef in ws
    int nb = 512;
    while (nb > 8 && ((size_t)nb * 32768 + 32768) > ws_size) nb >>= 1;

    float* part = ws;                          // nb * 8192 floats
    float* coef = ws + (size_t)nb * 8192;      // 8192 floats

    fno_fwd<<<nb, 256, 0, stream>>>(u, part, nb);
    fno_coef<<<64, 256, 0, stream>>>(part, nb, K, W, u, y, coef);
    fno_inv<<<1024, 256, 0, stream>>>(coef, out);
}